// Round 1
// baseline (1313.997 us; speedup 1.0000x reference)
//
#include <hip/hip_runtime.h>

#define NB 4096
#define NT 1024
#define NH 16

// sigma(z) = rcp(1 + exp2(-log2e * z));  tanh(z) = 2*sigma(2z) - 1
// Per-lane constants kpre/kA/kB select sigmoid (gates i,f,o) vs tanh (gate g).
#define GATE(accv, creg, hout) {                                              \
    float e_ = __builtin_amdgcn_exp2f((accv) * kpre);                         \
    float r_ = __builtin_amdgcn_rcpf(1.0f + e_);                              \
    float a_ = fmaf(r_, kA, kB);                                              \
    int ai_ = __float_as_int(a_);                                             \
    float iv_ = __int_as_float(__builtin_amdgcn_ds_bpermute(a_i, ai_));       \
    float fv_ = __int_as_float(__builtin_amdgcn_ds_bpermute(a_f, ai_));       \
    float gv_ = __int_as_float(__builtin_amdgcn_ds_bpermute(a_g, ai_));       \
    float ov_ = __int_as_float(__builtin_amdgcn_ds_bpermute(a_o, ai_));       \
    creg = fmaf(fv_, creg, iv_ * gv_);                                        \
    float e2_ = __builtin_amdgcn_exp2f(creg * -2.88539008177792681f);         \
    float r2_ = __builtin_amdgcn_rcpf(1.0f + e2_);                            \
    hout = ov_ * fmaf(r2_, 2.0f, -1.0f);                                      \
}

__global__ __launch_bounds__(256, 2) void lstm3_kernel(
    const float* __restrict__ x,
    const float* __restrict__ h0,
    const float* __restrict__ c0,
    const float* __restrict__ Wih0, const float* __restrict__ Whh0,
    const float* __restrict__ bih0, const float* __restrict__ bhh0,
    const float* __restrict__ Wih1, const float* __restrict__ Whh1,
    const float* __restrict__ bih1, const float* __restrict__ bhh1,
    const float* __restrict__ Wih2, const float* __restrict__ Whh2,
    const float* __restrict__ bih2, const float* __restrict__ bhh2,
    const float* __restrict__ Wfc,  const float* __restrict__ bfc,
    float* __restrict__ out)
{
    __shared__ float ldsH[3][4][64];   // per-wave h exchange (slots 0..15 are read)
    __shared__ float ldsX[4][64];      // per-wave x staging: 32 steps * 2 floats

    const int lane = threadIdx.x & 63;
    const int wv   = threadIdx.x >> 6;
    const int b    = (blockIdx.x << 2) + wv;
    const int j    = lane & 15;
    const int grp  = lane >> 4;        // 0:i 1:f 2:g 3:o

    const float kpre = (grp == 2) ? -2.88539008177792681f : -1.44269504088896340f;
    const float kA   = (grp == 2) ? 2.0f : 1.0f;
    const float kB   = (grp == 2) ? -1.0f : 0.0f;
    const int a_i = j * 4, a_f = (j + 16) * 4, a_g = (j + 32) * 4, a_o = (j + 48) * 4;

    // ---- load per-lane weight rows (gate row g == lane) ----
    float wih0[2], whh0[16], wih1[16], whh1[16], wih2[16], whh2[16];
    wih0[0] = Wih0[lane * 2 + 0];
    wih0[1] = Wih0[lane * 2 + 1];
#pragma unroll
    for (int k = 0; k < 16; ++k) {
        whh0[k] = Whh0[lane * 16 + k];
        wih1[k] = Wih1[lane * 16 + k];
        whh1[k] = Whh1[lane * 16 + k];
        wih2[k] = Wih2[lane * 16 + k];
        whh2[k] = Whh2[lane * 16 + k];
    }
    const float bias0 = bih0[lane] + bhh0[lane];
    const float bias1 = bih1[lane] + bhh1[lane];
    const float bias2 = bih2[lane] + bhh2[lane];

    // ---- initial state ----
    float c0r = c0[0 * NB * NH + b * NH + j];
    float c1r = c0[1 * NB * NH + b * NH + j];
    float c2r = c0[2 * NB * NH + b * NH + j];
    ldsH[0][wv][lane] = h0[0 * NB * NH + b * NH + j];
    ldsH[1][wv][lane] = h0[1 * NB * NH + b * NH + j];
    ldsH[2][wv][lane] = h0[2 * NB * NH + b * NH + j];
    __builtin_amdgcn_wave_barrier();

    // prefetch x chunk 0 (64 floats = 32 timesteps * 2 comps)
    float xpre = x[(size_t)b * (NT * 2) + lane];

    for (int ch = 0; ch < (NT * 2) / 64; ++ch) {
        ldsX[wv][lane] = xpre;
        __builtin_amdgcn_wave_barrier();
        if (ch + 1 < (NT * 2) / 64)
            xpre = x[(size_t)b * (NT * 2) + (ch + 1) * 64 + lane];

#pragma unroll 1
        for (int s = 0; s < 32; ++s) {
            const float xa = ldsX[wv][s * 2 + 0];
            const float xb = ldsX[wv][s * 2 + 1];

            // ================= layer 0 =================
            float hp[16];
#pragma unroll
            for (int q = 0; q < 4; ++q) {
                float4 v = *(const float4*)&ldsH[0][wv][q * 4];
                hp[q * 4 + 0] = v.x; hp[q * 4 + 1] = v.y;
                hp[q * 4 + 2] = v.z; hp[q * 4 + 3] = v.w;
            }
            float acc = fmaf(wih0[0], xa, fmaf(wih0[1], xb, bias0));
#pragma unroll
            for (int k = 0; k < 16; ++k) acc = fmaf(whh0[k], hp[k], acc);
            float hn0;
            GATE(acc, c0r, hn0);
            ldsH[0][wv][lane] = hn0;
            __builtin_amdgcn_wave_barrier();

            // ================= layer 1 =================
#pragma unroll
            for (int q = 0; q < 4; ++q) {
                float4 v = *(const float4*)&ldsH[1][wv][q * 4];
                hp[q * 4 + 0] = v.x; hp[q * 4 + 1] = v.y;
                hp[q * 4 + 2] = v.z; hp[q * 4 + 3] = v.w;
            }
            acc = bias1;
#pragma unroll
            for (int k = 0; k < 16; ++k) acc = fmaf(whh1[k], hp[k], acc);
            float xh[16];
#pragma unroll
            for (int q = 0; q < 4; ++q) {
                float4 v = *(const float4*)&ldsH[0][wv][q * 4];
                xh[q * 4 + 0] = v.x; xh[q * 4 + 1] = v.y;
                xh[q * 4 + 2] = v.z; xh[q * 4 + 3] = v.w;
            }
#pragma unroll
            for (int k = 0; k < 16; ++k) acc = fmaf(wih1[k], xh[k], acc);
            float hn1;
            GATE(acc, c1r, hn1);
            ldsH[1][wv][lane] = hn1;
            __builtin_amdgcn_wave_barrier();

            // ================= layer 2 =================
#pragma unroll
            for (int q = 0; q < 4; ++q) {
                float4 v = *(const float4*)&ldsH[2][wv][q * 4];
                hp[q * 4 + 0] = v.x; hp[q * 4 + 1] = v.y;
                hp[q * 4 + 2] = v.z; hp[q * 4 + 3] = v.w;
            }
            acc = bias2;
#pragma unroll
            for (int k = 0; k < 16; ++k) acc = fmaf(whh2[k], hp[k], acc);
#pragma unroll
            for (int q = 0; q < 4; ++q) {
                float4 v = *(const float4*)&ldsH[1][wv][q * 4];
                xh[q * 4 + 0] = v.x; xh[q * 4 + 1] = v.y;
                xh[q * 4 + 2] = v.z; xh[q * 4 + 3] = v.w;
            }
#pragma unroll
            for (int k = 0; k < 16; ++k) acc = fmaf(wih2[k], xh[k], acc);
            float hn2;
            GATE(acc, c2r, hn2);
            ldsH[2][wv][lane] = hn2;
            __builtin_amdgcn_wave_barrier();
        }
    }

    // ---- epilogue: out[b] = Wfc . h2[T-1] + bfc ----
    if (lane == 0) {
        float s = bfc[0];
#pragma unroll
        for (int k = 0; k < 16; ++k) s = fmaf(ldsH[2][wv][k], Wfc[k], s);
        out[b] = s;
    }
}

extern "C" void kernel_launch(void* const* d_in, const int* in_sizes, int n_in,
                              void* d_out, int out_size, void* d_ws, size_t ws_size,
                              hipStream_t stream) {
    (void)in_sizes; (void)n_in; (void)d_ws; (void)ws_size; (void)out_size;
    const float* x    = (const float*)d_in[0];
    const float* h0   = (const float*)d_in[1];
    const float* c0   = (const float*)d_in[2];
    const float* Wih0 = (const float*)d_in[3];
    const float* Whh0 = (const float*)d_in[4];
    const float* bih0 = (const float*)d_in[5];
    const float* bhh0 = (const float*)d_in[6];
    const float* Wih1 = (const float*)d_in[7];
    const float* Whh1 = (const float*)d_in[8];
    const float* bih1 = (const float*)d_in[9];
    const float* bhh1 = (const float*)d_in[10];
    const float* Wih2 = (const float*)d_in[11];
    const float* Whh2 = (const float*)d_in[12];
    const float* bih2 = (const float*)d_in[13];
    const float* bhh2 = (const float*)d_in[14];
    const float* Wfc  = (const float*)d_in[15];
    const float* bfc  = (const float*)d_in[16];
    float* out = (float*)d_out;

    lstm3_kernel<<<NB / 4, 256, 0, stream>>>(
        x, h0, c0, Wih0, Whh0, bih0, bhh0, Wih1, Whh1, bih1, bhh1,
        Wih2, Whh2, bih2, bhh2, Wfc, bfc, out);
}

// Round 2
// 1026.227 us; speedup vs baseline: 1.2804x; 1.2804x over previous
//
#include <hip/hip_runtime.h>

#define NB 4096
#define NT 1024

typedef float f2 __attribute__((ext_vector_type(2)));
typedef float f4 __attribute__((ext_vector_type(4)));

// Quad gate layout: lane = 4*j + g, g in {0:i, 1:f, 2:g~, 3:o}, j = hidden unit.
// After per-lane activation, broadcast the 4 gate values within each quad via DPP.
#define GATE(accv, creg, hout) {                                              \
    float e_ = __builtin_amdgcn_exp2f((accv) * kpre);                         \
    float r_ = __builtin_amdgcn_rcpf(1.0f + e_);                              \
    float a_ = fmaf(r_, kA, kB);                                              \
    int ai_ = __float_as_int(a_);                                             \
    float iv_ = __int_as_float(__builtin_amdgcn_mov_dpp(ai_, 0x00, 0xF, 0xF, 0)); \
    float fv_ = __int_as_float(__builtin_amdgcn_mov_dpp(ai_, 0x55, 0xF, 0xF, 0)); \
    float gv_ = __int_as_float(__builtin_amdgcn_mov_dpp(ai_, 0xAA, 0xF, 0xF, 0)); \
    float ov_ = __int_as_float(__builtin_amdgcn_mov_dpp(ai_, 0xFF, 0xF, 0xF, 0)); \
    creg = fmaf(fv_, creg, iv_ * gv_);                                        \
    float e2_ = __builtin_amdgcn_exp2f(creg * -2.88539008177792681f);         \
    float r2_ = __builtin_amdgcn_rcpf(1.0f + e2_);                            \
    hout = ov_ * fmaf(r2_, 2.0f, -1.0f);                                      \
}

// Read the 16-float h vector (slots 0..15, wave-uniform broadcast) as 8 f2 pairs.
#define LOAD_H(dst, L) {                                                      \
    _Pragma("unroll")                                                         \
    for (int q4_ = 0; q4_ < 4; ++q4_) {                                       \
        f4 v_ = *(const f4*)&ldsH[L][wv][q4_ * 4];                            \
        dst[q4_ * 2 + 0] = __builtin_shufflevector(v_, v_, 0, 1);             \
        dst[q4_ * 2 + 1] = __builtin_shufflevector(v_, v_, 2, 3);             \
    }                                                                         \
}

__global__ __launch_bounds__(256, 4) void lstm3_kernel(
    const float* __restrict__ x,
    const float* __restrict__ h0,
    const float* __restrict__ c0,
    const float* __restrict__ Wih0, const float* __restrict__ Whh0,
    const float* __restrict__ bih0, const float* __restrict__ bhh0,
    const float* __restrict__ Wih1, const float* __restrict__ Whh1,
    const float* __restrict__ bih1, const float* __restrict__ bhh1,
    const float* __restrict__ Wih2, const float* __restrict__ Whh2,
    const float* __restrict__ bih2, const float* __restrict__ bhh2,
    const float* __restrict__ Wfc,  const float* __restrict__ bfc,
    float* __restrict__ out)
{
    __shared__ float ldsH[3][4][64];   // h exchange; slots 0..15 hold h[0..15]
    __shared__ float ldsX[4][64];      // x staging: 32 steps * 2 floats per wave

    const int lane = threadIdx.x & 63;
    const int wv   = threadIdx.x >> 6;
    const int b    = (blockIdx.x << 2) + wv;
    const int q    = lane >> 2;        // hidden unit 0..15
    const int g    = lane & 3;         // gate 0:i 1:f 2:g 3:o
    const int row  = g * 16 + q;       // PyTorch gate-row index

    const float kpre = (g == 2) ? -2.88539008177792681f : -1.44269504088896340f;
    const float kA   = (g == 2) ? 2.0f : 1.0f;
    const float kB   = (g == 2) ? -1.0f : 0.0f;

    // ---- per-lane weight rows, packed as f2 pairs (VGPR-resident) ----
    f2 wi0;
    wi0.x = Wih0[row * 2 + 0];
    wi0.y = Wih0[row * 2 + 1];
    f2 wh0[8], wi1[8], wh1[8], wi2[8], wh2[8];
#pragma unroll
    for (int k = 0; k < 8; ++k) {
        wh0[k].x = Whh0[row * 16 + 2 * k]; wh0[k].y = Whh0[row * 16 + 2 * k + 1];
        wi1[k].x = Wih1[row * 16 + 2 * k]; wi1[k].y = Wih1[row * 16 + 2 * k + 1];
        wh1[k].x = Whh1[row * 16 + 2 * k]; wh1[k].y = Whh1[row * 16 + 2 * k + 1];
        wi2[k].x = Wih2[row * 16 + 2 * k]; wi2[k].y = Wih2[row * 16 + 2 * k + 1];
        wh2[k].x = Whh2[row * 16 + 2 * k]; wh2[k].y = Whh2[row * 16 + 2 * k + 1];
    }
    const float bias0 = bih0[row] + bhh0[row];
    const float bias1 = bih1[row] + bhh1[row];
    const float bias2 = bih2[row] + bhh2[row];

    // ---- initial state ----
    float c0r = c0[0 * NB * 16 + b * 16 + q];
    float c1r = c0[1 * NB * 16 + b * 16 + q];
    float c2r = c0[2 * NB * 16 + b * 16 + q];
    ldsH[0][wv][lane] = h0[0 * NB * 16 + b * 16 + (lane & 15)];
    ldsH[1][wv][lane] = h0[1 * NB * 16 + b * 16 + (lane & 15)];
    ldsH[2][wv][lane] = h0[2 * NB * 16 + b * 16 + (lane & 15)];
    const int hslot = g * 16 + q;      // write slot; slots 0..15 are h[0..15]
    __builtin_amdgcn_wave_barrier();

    // prefetch x chunk 0 (64 floats = 32 timesteps * 2 comps)
    float xpre = x[(size_t)b * (NT * 2) + lane];

    for (int ch = 0; ch < (NT * 2) / 64; ++ch) {
        ldsX[wv][lane] = xpre;
        __builtin_amdgcn_wave_barrier();
        if (ch + 1 < (NT * 2) / 64)
            xpre = x[(size_t)b * (NT * 2) + (ch + 1) * 64 + lane];

#pragma unroll 2
        for (int s = 0; s < 32; ++s) {
            const f2 x2 = ((const f2*)&ldsX[wv][0])[s];

            // ================= layer 0 =================
            f2 hp[8];
            LOAD_H(hp, 0);
            f2 aA = wi0 * x2;  aA.x += bias0;
            f2 aB = wh0[1] * hp[1];
            f2 aC = wh0[2] * hp[2];
            f2 aD = wh0[3] * hp[3];
            aA = wh0[0] * hp[0] + aA;
            aB = wh0[4] * hp[4] + aB;
            aC = wh0[5] * hp[5] + aC;
            aD = wh0[6] * hp[6] + aD;
            aA = wh0[7] * hp[7] + aA;
            f2 sum2 = (aA + aB) + (aC + aD);
            float acc = sum2.x + sum2.y;
            float hn0;
            GATE(acc, c0r, hn0);
            ldsH[0][wv][hslot] = hn0;
            __builtin_amdgcn_wave_barrier();

            // ================= layer 1 =================
            f2 xh[8];
            LOAD_H(hp, 1);
            LOAD_H(xh, 0);
            aA = wh1[0] * hp[0]; aA.x += bias1;
            aB = wh1[1] * hp[1];
            aC = wh1[2] * hp[2];
            aD = wh1[3] * hp[3];
            aA = wh1[4] * hp[4] + aA;
            aB = wh1[5] * hp[5] + aB;
            aC = wh1[6] * hp[6] + aC;
            aD = wh1[7] * hp[7] + aD;
            aA = wi1[0] * xh[0] + aA;
            aB = wi1[1] * xh[1] + aB;
            aC = wi1[2] * xh[2] + aC;
            aD = wi1[3] * xh[3] + aD;
            aA = wi1[4] * xh[4] + aA;
            aB = wi1[5] * xh[5] + aB;
            aC = wi1[6] * xh[6] + aC;
            aD = wi1[7] * xh[7] + aD;
            sum2 = (aA + aB) + (aC + aD);
            acc = sum2.x + sum2.y;
            float hn1;
            GATE(acc, c1r, hn1);
            ldsH[1][wv][hslot] = hn1;
            __builtin_amdgcn_wave_barrier();

            // ================= layer 2 =================
            LOAD_H(hp, 2);
            LOAD_H(xh, 1);
            aA = wh2[0] * hp[0]; aA.x += bias2;
            aB = wh2[1] * hp[1];
            aC = wh2[2] * hp[2];
            aD = wh2[3] * hp[3];
            aA = wh2[4] * hp[4] + aA;
            aB = wh2[5] * hp[5] + aB;
            aC = wh2[6] * hp[6] + aC;
            aD = wh2[7] * hp[7] + aD;
            aA = wi2[0] * xh[0] + aA;
            aB = wi2[1] * xh[1] + aB;
            aC = wi2[2] * xh[2] + aC;
            aD = wi2[3] * xh[3] + aD;
            aA = wi2[4] * xh[4] + aA;
            aB = wi2[5] * xh[5] + aB;
            aC = wi2[6] * xh[6] + aC;
            aD = wi2[7] * xh[7] + aD;
            sum2 = (aA + aB) + (aC + aD);
            acc = sum2.x + sum2.y;
            float hn2;
            GATE(acc, c2r, hn2);
            ldsH[2][wv][hslot] = hn2;
            __builtin_amdgcn_wave_barrier();
        }
    }

    // ---- epilogue: out[b] = Wfc . h2[T-1] + bfc ----
    if (lane == 0) {
        float s = bfc[0];
#pragma unroll
        for (int k = 0; k < 16; ++k) s = fmaf(ldsH[2][wv][k], Wfc[k], s);
        out[b] = s;
    }
}

extern "C" void kernel_launch(void* const* d_in, const int* in_sizes, int n_in,
                              void* d_out, int out_size, void* d_ws, size_t ws_size,
                              hipStream_t stream) {
    (void)in_sizes; (void)n_in; (void)d_ws; (void)ws_size; (void)out_size;
    const float* x    = (const float*)d_in[0];
    const float* h0   = (const float*)d_in[1];
    const float* c0   = (const float*)d_in[2];
    const float* Wih0 = (const float*)d_in[3];
    const float* Whh0 = (const float*)d_in[4];
    const float* bih0 = (const float*)d_in[5];
    const float* bhh0 = (const float*)d_in[6];
    const float* Wih1 = (const float*)d_in[7];
    const float* Whh1 = (const float*)d_in[8];
    const float* bih1 = (const float*)d_in[9];
    const float* bhh1 = (const float*)d_in[10];
    const float* Wih2 = (const float*)d_in[11];
    const float* Whh2 = (const float*)d_in[12];
    const float* bih2 = (const float*)d_in[13];
    const float* bhh2 = (const float*)d_in[14];
    const float* Wfc  = (const float*)d_in[15];
    const float* bfc  = (const float*)d_in[16];
    float* out = (float*)d_out;

    lstm3_kernel<<<NB / 4, 256, 0, stream>>>(
        x, h0, c0, Wih0, Whh0, bih0, bhh0, Wih1, Whh1, bih1, bhh1,
        Wih2, Whh2, bih2, bhh2, Wfc, bfc, out);
}